// Round 4
// baseline (311.048 us; speedup 1.0000x reference)
//
#include <hip/hip_runtime.h>

typedef _Float16 f16;
typedef f16 f16x8 __attribute__((ext_vector_type(8)));
typedef f16 f16x4v __attribute__((ext_vector_type(4)));
typedef float f32x4 __attribute__((ext_vector_type(4)));

// async global->LDS, 16B per lane. LDS dest is wave-uniform base; HW scatters
// lane i's 16B to base + i*16.
__device__ __forceinline__ void async_ld16(const void* g, void* l) {
    __builtin_amdgcn_global_load_lds(
        (const __attribute__((address_space(1))) unsigned int*)g,
        (__attribute__((address_space(3))) unsigned int*)l, 16, 0, 0);
}

// C[m,n] = sum_k A[m,k] * Bt[n,k], tile 128(m) x TBN(n) x 32(k).
// Operand order chosen so the C/D reg dim (row = quad*4+reg, m89-verified)
// is the CONTIGUOUS dim of each output -> vectorized stores.
// MODE 0 (TBN=128): fused QKV. A = concat(Wq,Wk,Wv) [3072][1024], B = inp
//        [8192][1024]. seg=mBase>>10 routes to Q16/K16/V16 row-major
//        [t][f_local] (+bias[f], f16x4 stores).
// MODE 2 (TBN=64): scores. A = K [2048][1024], B = Q. P[q][k] = exp(s/32)
//        (causal-zeroed k>q), f16x4 stores; rowsum[q] += partials (atomics).
//        Skip tile if all k>q (bx < 2*by).
// MODE 3 (TBN=64): PV. A = Vt [1024][2048], B = P [2048][2048].
//        out[q][e] = acc/rowsum[q], float4 stores; kmax=(bx+1)*64.
template <int MODE>
__global__ __launch_bounds__(256) void gemm_bt(
    const f16* __restrict__ A, long strideAb, int lda,
    const f16* __restrict__ Bt, long strideBb, int ldb,
    const float* __restrict__ b_q, const float* __restrict__ b_k,
    const float* __restrict__ b_v, float* __restrict__ rowsum,
    void* __restrict__ C0, void* __restrict__ C1, void* __restrict__ C2,
    long strideCb, int K,
    const int* __restrict__ maskedp)
{
    constexpr int TBN = (MODE == 0) ? 128 : 64;
    constexpr int NI  = (MODE == 0) ? 4 : 2;
    const int bz = blockIdx.z, by = blockIdx.y;
    const int bx = (MODE == 3) ? (gridDim.x - 1 - blockIdx.x) : blockIdx.x;
    const int masked = maskedp ? *maskedp : 1;
    if (MODE == 2 && masked && bx < 2 * by) return;   // fully-masked tile
    int kmax = K;
    if (MODE == 3 && masked) kmax = min(K, (bx + 1) * 64);

    A  += (long)bz * strideAb;
    Bt += (long)bz * strideBb;

    __shared__ __align__(16) f16 smem[(128 + TBN) * 32];
    f16* sA = smem;
    f16* sB = smem + 128 * 32;

    const int tid  = threadIdx.x;
    const int wave = tid >> 6, lane = tid & 63;
    const int wrow = (MODE == 0) ? (wave >> 1) : wave;
    const int wcol = (MODE == 0) ? (wave & 1) : 0;
    const int quad = lane >> 4, l16 = lane & 15;
    const int mBase = by * 128, nBase = bx * TBN;

    f32x4 acc[NI][4];
#pragma unroll
    for (int i = 0; i < NI; ++i)
#pragma unroll
        for (int j = 0; j < 4; ++j)
            acc[i][j] = (f32x4){0.f, 0.f, 0.f, 0.f};

    // pointer-bumped staging addresses (+32 f16 per K-iter)
    const f16* aP[2];
#pragma unroll
    for (int r = 0; r < 2; ++r)
        aP[r] = A + (long)(mBase + ((r * 256 + tid) >> 2)) * lda + ((tid * 8) & 31);
    const f16* bP[TBN / 64];
#pragma unroll
    for (int r = 0; r < TBN / 64; ++r)
        bP[r] = Bt + (long)(nBase + ((r * 256 + tid) >> 2)) * ldb + ((tid * 8) & 31);

    f16* sAd = &sA[wave * 512];
    f16* sBd = &sB[wave * 512];

    const int nT = kmax >> 5;
    for (int kt = 0; kt < nT; ++kt) {
        async_ld16(aP[0], sAd);
        async_ld16(aP[1], sAd + 2048);
        aP[0] += 32;  aP[1] += 32;
        async_ld16(bP[0], sBd);
        bP[0] += 32;
        if (TBN == 128) { async_ld16(bP[1], sBd + 2048); bP[1] += 32; }
        __syncthreads();

        f16x8 af[NI], bf[4];
#pragma unroll
        for (int i = 0; i < NI; ++i)
            af[i] = *(const f16x8*)&sA[(wrow * (16 * NI) + i * 16 + l16) * 32 + quad * 8];
#pragma unroll
        for (int j = 0; j < 4; ++j)
            bf[j] = *(const f16x8*)&sB[(wcol * 64 + j * 16 + l16) * 32 + quad * 8];
#pragma unroll
        for (int i = 0; i < NI; ++i)
#pragma unroll
            for (int j = 0; j < 4; ++j)
                acc[i][j] = __builtin_amdgcn_mfma_f32_16x16x32_f16(af[i], bf[j], acc[i][j], 0, 0, 0);
        __syncthreads();
    }

    // ---- epilogues: reg dim (quad*4+r) == contiguous output dim ----
    if (MODE == 0) {
        const int seg = mBase >> 10;       // 0=Q 1=K 2=V
        const int fl  = mBase & 1023;
        const float* bs = (seg == 0) ? b_q : (seg == 1) ? b_k : b_v;
        f16* dst = (seg == 0) ? (f16*)C0 : (seg == 1) ? (f16*)C1 : (f16*)C2;
#pragma unroll
        for (int i = 0; i < 4; ++i) {
            const int fo = fl + wrow * 64 + i * 16 + quad * 4;
            const f32x4 bi = *(const f32x4*)&bs[fo];
#pragma unroll
            for (int j = 0; j < 4; ++j) {
                const long t = nBase + wcol * 64 + j * 16 + l16;
                f16x4v pk;
#pragma unroll
                for (int r = 0; r < 4; ++r) pk[r] = (f16)(acc[i][j][r] + bi[r]);
                *(f16x4v*)&dst[t * 1024 + fo] = pk;
            }
        }
    } else if (MODE == 2) {
        f16* P = (f16*)C0 + (long)bz * strideCb;
        float* rsb = rowsum + bz * 2048;
        float cs[4] = {0.f, 0.f, 0.f, 0.f};
#pragma unroll
        for (int i = 0; i < NI; ++i) {
            const int rowb = mBase + wrow * 32 + i * 16 + quad * 4;
#pragma unroll
            for (int j = 0; j < 4; ++j) {
                const int col = nBase + j * 16 + l16;
                f16x4v pk;
#pragma unroll
                for (int r = 0; r < 4; ++r) {
                    float e = __expf(acc[i][j][r] * 0.03125f);
                    if (masked && (rowb + r) > col) e = 0.f;
                    const f16 hv = (f16)e;
                    pk[r] = hv;
                    cs[j] += (float)hv;
                }
                *(f16x4v*)&P[(long)col * 2048 + rowb] = pk;
            }
        }
#pragma unroll
        for (int j = 0; j < 4; ++j) {
            float s = cs[j];           // quads share the same col set
            s += __shfl_xor(s, 16);
            s += __shfl_xor(s, 32);
            if (quad == 0) atomicAdd(&rsb[nBase + j * 16 + l16], s);
        }
    } else {  // MODE 3
        float* O = (float*)C0 + (long)bz * strideCb;
        const float* rsb = rowsum + bz * 2048;
#pragma unroll
        for (int j = 0; j < 4; ++j) {
            const int col = nBase + j * 16 + l16;
            const float inv = 1.f / rsb[col];
#pragma unroll
            for (int i = 0; i < NI; ++i) {
                const int rowb = mBase + wrow * 32 + i * 16 + quad * 4;
                f32x4 v = acc[i][j] * inv;
                *(f32x4*)&O[(long)col * 1024 + rowb] = v;
            }
        }
    }
}

// V16 [b*2048+s][1024 f] -> Vt [b][f][s], 64x64 LDS tiles.
__global__ __launch_bounds__(256) void transpose_v(const f16* __restrict__ V16,
                                                   f16* __restrict__ Vt)
{
    __shared__ f16 t[64 * 65];
    const int s0 = blockIdx.x * 64, f0 = blockIdx.y * 64, b = blockIdx.z;
    const int tid = threadIdx.x;
    const int sl = tid >> 3, ch = tid & 7;
    const f16* src = V16 + ((long)b * 2048 + s0 + sl) * 1024 + f0 + ch * 8;
    const f16x8 v0 = *(const f16x8*)src;
    const f16x8 v1 = *(const f16x8*)(src + (long)32 * 1024);
#pragma unroll
    for (int e = 0; e < 8; ++e) {
        t[sl * 65 + ch * 8 + e]        = v0[e];
        t[(sl + 32) * 65 + ch * 8 + e] = v1[e];
    }
    __syncthreads();
    const int fo = tid >> 3, sc = tid & 7;
    f16x8 o0, o1;
#pragma unroll
    for (int e = 0; e < 8; ++e) {
        o0[e] = t[(sc * 8 + e) * 65 + fo];
        o1[e] = t[(sc * 8 + e) * 65 + fo + 32];
    }
    f16* dst = Vt + ((long)b * 1024 + f0 + fo) * 2048 + s0 + sc * 8;
    *(f16x8*)dst = o0;
    *(f16x8*)(dst + (long)32 * 2048) = o1;
}

__global__ void cvt_inp(const float* __restrict__ in, f16* __restrict__ out, int n4)
{
    const int i = blockIdx.x * blockDim.x + threadIdx.x;
    if (i >= n4) return;
    const float4 v = ((const float4*)in)[i];
    f16x4v o;
    o[0] = (f16)v.x; o[1] = (f16)v.y; o[2] = (f16)v.z; o[3] = (f16)v.w;
    ((f16x4v*)out)[i] = o;
}

// three 1024x1024 weight matrices -> contiguous f16 [3072][1024]
__global__ void cvt_w3(const float* __restrict__ W0, const float* __restrict__ W1,
                       const float* __restrict__ W2, f16* __restrict__ out)
{
    const int bxx = blockIdx.x;            // 3072 blocks
    const int which = bxx >> 10;
    const float* src = (which == 0) ? W0 : (which == 1) ? W1 : W2;
    const int i = (bxx & 1023) * 256 + threadIdx.x;
    const float4 v = ((const float4*)src)[i];
    f16x4v o;
    o[0] = (f16)v.x; o[1] = (f16)v.y; o[2] = (f16)v.z; o[3] = (f16)v.w;
    ((f16x4v*)(out + (long)which * 1024 * 1024))[i] = o;
}

extern "C" void kernel_launch(void* const* d_in, const int* in_sizes, int n_in,
                              void* d_out, int out_size, void* d_ws, size_t ws_size,
                              hipStream_t stream)
{
    const float* inp = (const float*)d_in[0];
    const int* masked = (const int*)d_in[1];
    const float* Wq = (const float*)d_in[2];
    const float* bq = (const float*)d_in[3];
    const float* Wk = (const float*)d_in[4];
    const float* bk = (const float*)d_in[5];
    const float* Wv = (const float*)d_in[6];
    const float* bv = (const float*)d_in[7];
    float* out = (float*)d_out;

    const int Bb = 4, S = 2048, E = 1024;
    const long nTok = (long)Bb * S;   // 8192

    // workspace (~102 MB). W3 segments must stay contiguous (one A operand).
    // Vt ALIASES inp16: inp16 is dead after the QKV GEMM.
    char* ws = (char*)d_ws;
    f16* inp16 = (f16*)ws;   ws += nTok * E * 2;         // 16 MB
    f16* W3    = (f16*)ws;   ws += (long)3 * E * E * 2;  //  6 MB
    f16* Q16   = (f16*)ws;   ws += nTok * E * 2;         // 16 MB
    f16* K16   = (f16*)ws;   ws += nTok * E * 2;         // 16 MB
    f16* V16   = (f16*)ws;   ws += nTok * E * 2;         // 16 MB [t][f]
    f16* P16   = (f16*)ws;   ws += (long)Bb * S * S * 2; // 32 MB
    float* rsum = (float*)ws; ws += nTok * 4;            // 32 KB
    f16* Vt    = inp16;                                  // alias, [b][f][s]

    dim3 blk(256);

    hipMemsetAsync(rsum, 0, nTok * 4, stream);
    cvt_inp<<<(int)(nTok * E / 4 / 256), blk, 0, stream>>>(inp, inp16, (int)(nTok * E / 4));
    cvt_w3<<<3 * 1024, blk, 0, stream>>>(Wq, Wk, Wv, W3);

    // fused QKV: A = W3 (3072x1024), B = inp (8192x1024)
    gemm_bt<0><<<dim3(64, 24, 1), blk, 0, stream>>>(
        W3, 0, E, inp16, 0, E, bq, bk, bv, nullptr,
        Q16, K16, V16, 0, E, nullptr);

    transpose_v<<<dim3(32, 16, Bb), blk, 0, stream>>>(V16, Vt);

    // P = exp(QK^T/32): A = K (k rows), B = Q (q cols)
    gemm_bt<2><<<dim3(32, 16, Bb), blk, 0, stream>>>(
        K16, (long)S * E, E, Q16, (long)S * E, E, nullptr, nullptr, nullptr, rsum,
        P16, nullptr, nullptr, (long)S * S, E, masked);

    // out = (P @ V)/rowsum: A = Vt (e rows), B = P (q cols)
    gemm_bt<3><<<dim3(32, 8, Bb), blk, 0, stream>>>(
        Vt, (long)E * S, S, P16, (long)S * S, S, nullptr, nullptr, nullptr, rsum,
        out, nullptr, nullptr, (long)S * E, S, masked);
}

// Round 5
// 280.737 us; speedup vs baseline: 1.1080x; 1.1080x over previous
//
#include <hip/hip_runtime.h>

typedef _Float16 f16;
typedef f16 f16x8 __attribute__((ext_vector_type(8)));
typedef f16 f16x4v __attribute__((ext_vector_type(4)));
typedef float f32x4 __attribute__((ext_vector_type(4)));

// async global->LDS, 16B per lane. LDS dest is wave-uniform base; HW scatters
// lane i's 16B to base + i*16. (No padding possible -> keep BK=32 layout.)
__device__ __forceinline__ void async_ld16(const void* g, void* l) {
    __builtin_amdgcn_global_load_lds(
        (const __attribute__((address_space(1))) unsigned int*)g,
        (__attribute__((address_space(3))) unsigned int*)l, 16, 0, 0);
}

// C[m,n] = sum_k A[m,k] * Bt[n,k], tile 128 x TBN, K-step 64 = 2 x BK32
// sub-tiles per barrier pair (halves the barrier-drain events vs BK=32;
// sub-tiles keep the stride-32 layout so LDS reads stay 2-way-conflict-free).
// MODE 0 (TBN=128): fused QKV projection, N=3072. Segment (nBase>>10):
//       0 -> Q16 row-major (+b_q), 1 -> K16 row-major (+b_k),
//       2 -> Vt16 per-batch transposed [b][e][s] (+b_v) via LDS transpose.
// MODE 2 (TBN=64): P[q][k] = exp(score/32) f16, causal-zeroed k>q; per-row
//       partial sums atomicAdd'ed into rowsum (no max-sub needed: |s/32|<~4).
// MODE 3 (TBN=64): out = (P @ V) / rowsum[q], fp32; K-loop causal-limited.
template <int MODE, int TBN>
__global__ __launch_bounds__(256) void gemm_bt(
    const f16* __restrict__ A, long strideAb, int lda,
    const f16* __restrict__ Bt, long strideBb, int ldb,
    const float* __restrict__ b_q, const float* __restrict__ b_k,
    const float* __restrict__ b_v, float* __restrict__ rowsum,
    void* __restrict__ C0, void* __restrict__ C1, void* __restrict__ C2,
    long strideCb, int K,
    const int* __restrict__ maskedp)
{
    const int bx = blockIdx.x, bz = blockIdx.z;
    // heavy (long-K / unskipped) rows launch first for causal modes
    const int by = (MODE >= 2) ? (gridDim.y - 1 - blockIdx.y) : blockIdx.y;
    const int masked = maskedp ? *maskedp : 1;
    if (MODE == 2 && masked && bx > 2 * by + 1) return;  // fully-masked tile
    int kmax = K;
    if (MODE == 3 && masked) kmax = min(K, (by + 1) * 128);

    A  += (long)bz * strideAb;
    Bt += (long)bz * strideBb;

    // two BK=32 sub-tiles of A (128x32 each) + two of B (TBNx32 each)
    __shared__ __align__(16) f16 smem[(128 + TBN) * 64];
    f16* sA = smem;                    // halves at h*4096
    f16* sB = smem + 128 * 64;         // halves at h*(TBN*32)

    const int tid  = threadIdx.x;
    const int wave = tid >> 6, lane = tid & 63;
    const int wrow = (TBN == 128) ? (wave >> 1) : wave;
    const int wcol = (TBN == 128) ? (wave & 1) : 0;
    constexpr int NI = (TBN == 128) ? 4 : 2;      // 16-row blocks per wave
    const int quad = lane >> 4, l16 = lane & 15;
    const int mBase = by * 128, nBase = bx * TBN;

    f32x4 acc[NI][4];
#pragma unroll
    for (int i = 0; i < NI; ++i)
#pragma unroll
        for (int j = 0; j < 4; ++j)
            acc[i][j] = (f32x4){0.f, 0.f, 0.f, 0.f};

    // pointer-bumped staging addresses (+64 f16 per outer iter)
    const f16* aP[2];
#pragma unroll
    for (int r = 0; r < 2; ++r)
        aP[r] = A + (long)(mBase + ((r * 256 + tid) >> 2)) * lda + ((tid * 8) & 31);
    const f16* bP[TBN / 64];
#pragma unroll
    for (int r = 0; r < TBN / 64; ++r)
        bP[r] = Bt + (long)(nBase + ((r * 256 + tid) >> 2)) * ldb + ((tid * 8) & 31);

    const int ldsOff = wave * 512;     // (wave*64)*8

    const int nT = kmax >> 6;          // K-step 64
    for (int kt = 0; kt < nT; ++kt) {
#pragma unroll
        for (int h = 0; h < 2; ++h) {
#pragma unroll
            for (int r = 0; r < 2; ++r)
                async_ld16(aP[r] + h * 32, &sA[h * 4096 + r * 2048 + ldsOff]);
#pragma unroll
            for (int r = 0; r < TBN / 64; ++r)
                async_ld16(bP[r] + h * 32, &sB[h * (TBN * 32) + r * 2048 + ldsOff]);
        }
#pragma unroll
        for (int r = 0; r < 2; ++r) aP[r] += 64;
#pragma unroll
        for (int r = 0; r < TBN / 64; ++r) bP[r] += 64;
        __syncthreads();

#pragma unroll
        for (int h = 0; h < 2; ++h) {
            f16x8 af[NI], bf[4];
#pragma unroll
            for (int i = 0; i < NI; ++i)
                af[i] = *(const f16x8*)&sA[h * 4096 + (wrow * (16 * NI) + i * 16 + l16) * 32 + quad * 8];
#pragma unroll
            for (int j = 0; j < 4; ++j)
                bf[j] = *(const f16x8*)&sB[h * (TBN * 32) + (wcol * 64 + j * 16 + l16) * 32 + quad * 8];
#pragma unroll
            for (int i = 0; i < NI; ++i)
#pragma unroll
                for (int j = 0; j < 4; ++j)
                    acc[i][j] = __builtin_amdgcn_mfma_f32_16x16x32_f16(af[i], bf[j], acc[i][j], 0, 0, 0);
        }
        __syncthreads();
    }

    // ---- epilogues. C/D layout: col = lane&15, row = quad*4 + reg  [m89] ----
    if (MODE == 0) {
        const int seg = nBase >> 10;
        const float* bs = (seg == 0) ? b_q : (seg == 1) ? b_k : b_v;
        const int lcb = (nBase & 1023) + wcol * 64;
        float bvv[4];
#pragma unroll
        for (int j = 0; j < 4; ++j) bvv[j] = bs[lcb + j * 16 + l16];

        if (seg < 2) {
            // scalar stores, but 64 consecutive f16 per wave-instr: fully
            // line-coalesced (round-4's f16x4 row-scatter was SLOWER).
            f16* dst = (seg == 0) ? (f16*)C0 : (f16*)C1;
#pragma unroll
            for (int i = 0; i < NI; ++i)
#pragma unroll
                for (int j = 0; j < 4; ++j)
#pragma unroll
                    for (int r = 0; r < 4; ++r) {
                        const int row = mBase + wrow * 64 + i * 16 + quad * 4 + r;
                        const int lc = lcb + j * 16 + l16;
                        dst[(long)row * 1024 + lc] = (f16)(acc[i][j][r] + bvv[j]);
                    }
        } else {
            // V: transpose tile through LDS, store coalesced along s.
            // epiT: 64 e-rows x (128+8) s-cols f16 (stride 272 B)
            const int b = mBase >> 11, s0 = mBase & 2047;
            f16* epiT = smem;
#pragma unroll
            for (int h = 0; h < 2; ++h) {
                if (wcol == h) {
#pragma unroll
                    for (int i = 0; i < 4; ++i)
#pragma unroll
                        for (int j = 0; j < 4; ++j) {
                            f16x4v pk;
#pragma unroll
                            for (int r = 0; r < 4; ++r)
                                pk[r] = (f16)(acc[i][j][r] + bvv[j]);
                            const int e2 = j * 16 + l16;
                            const int sl = wrow * 64 + i * 16 + quad * 4;
                            *(f16x4v*)&epiT[e2 * 136 + sl] = pk;
                        }
                }
                __syncthreads();
                const int er = tid >> 2;
                f16* dst = (f16*)C2 +
                    ((long)b * 1024 + (nBase & 1023) + h * 64 + er) * 2048 + s0;
#pragma unroll
                for (int cc = 0; cc < 4; ++cc) {
                    const int ch = (tid & 3) + cc * 4;
                    *(f16x8*)&dst[ch * 8] = *(const f16x8*)&epiT[er * 136 + ch * 8];
                }
                __syncthreads();
            }
        }
    } else if (MODE == 2) {
        f16* Crow = (f16*)C0 + (long)bz * strideCb;
        float* rsb = rowsum + bz * 2048;
#pragma unroll
        for (int i = 0; i < NI; ++i) {
            float rs[4] = {0.f, 0.f, 0.f, 0.f};
#pragma unroll
            for (int j = 0; j < 4; ++j)
#pragma unroll
                for (int r = 0; r < 4; ++r) {
                    const int row = mBase + wrow * 32 + i * 16 + quad * 4 + r;
                    const int col = nBase + j * 16 + l16;
                    float e = __expf(acc[i][j][r] * 0.03125f);
                    if (masked && col > row) e = 0.f;
                    const f16 hv = (f16)e;
                    Crow[(long)row * 2048 + col] = hv;
                    rs[r] += (float)hv;
                }
#pragma unroll
            for (int r = 0; r < 4; ++r) {
                float s = rs[r];
                s += __shfl_xor(s, 1);
                s += __shfl_xor(s, 2);
                s += __shfl_xor(s, 4);
                s += __shfl_xor(s, 8);
                if (l16 == 0) {
                    const int row = mBase + wrow * 32 + i * 16 + quad * 4 + r;
                    atomicAdd(&rsb[row], s);
                }
            }
        }
    } else {  // MODE 3
        float* Crow = (float*)C0 + (long)bz * strideCb;
        const float* rsb = rowsum + bz * 2048;
#pragma unroll
        for (int i = 0; i < NI; ++i)
#pragma unroll
            for (int r = 0; r < 4; ++r) {
                const int row = mBase + wrow * 32 + i * 16 + quad * 4 + r;
                const float inv = 1.f / rsb[row];
#pragma unroll
                for (int j = 0; j < 4; ++j) {
                    const int col = nBase + j * 16 + l16;
                    Crow[(long)row * 1024 + col] = acc[i][j][r] * inv;
                }
            }
    }
}

__global__ void cvt_inp(const float* __restrict__ in, f16* __restrict__ out, int n4)
{
    const int i = blockIdx.x * blockDim.x + threadIdx.x;
    if (i >= n4) return;
    const float4 v = ((const float4*)in)[i];
    f16x4v o;
    o[0] = (f16)v.x; o[1] = (f16)v.y; o[2] = (f16)v.z; o[3] = (f16)v.w;
    ((f16x4v*)out)[i] = o;
}

// three 1024x1024 weight matrices -> contiguous f16 [3072][1024]
__global__ void cvt_w3(const float* __restrict__ W0, const float* __restrict__ W1,
                       const float* __restrict__ W2, f16* __restrict__ out)
{
    const int bxx = blockIdx.x;            // 3072 blocks
    const int which = bxx >> 10;
    const float* src = (which == 0) ? W0 : (which == 1) ? W1 : W2;
    const int i = (bxx & 1023) * 256 + threadIdx.x;
    const float4 v = ((const float4*)src)[i];
    f16x4v o;
    o[0] = (f16)v.x; o[1] = (f16)v.y; o[2] = (f16)v.z; o[3] = (f16)v.w;
    ((f16x4v*)(out + (long)which * 1024 * 1024))[i] = o;
}

extern "C" void kernel_launch(void* const* d_in, const int* in_sizes, int n_in,
                              void* d_out, int out_size, void* d_ws, size_t ws_size,
                              hipStream_t stream)
{
    const float* inp = (const float*)d_in[0];
    const int* masked = (const int*)d_in[1];
    const float* Wq = (const float*)d_in[2];
    const float* bq = (const float*)d_in[3];
    const float* Wk = (const float*)d_in[4];
    const float* bk = (const float*)d_in[5];
    const float* Wv = (const float*)d_in[6];
    const float* bv = (const float*)d_in[7];
    float* out = (float*)d_out;

    const int Bb = 4, S = 2048, E = 1024;
    const long nTok = (long)Bb * S;   // 8192

    // workspace (~102 MB). W3 segments must stay contiguous (one Bt operand).
    char* ws = (char*)d_ws;
    f16* inp16 = (f16*)ws;   ws += nTok * E * 2;         // 16 MB
    f16* W3    = (f16*)ws;   ws += (long)3 * E * E * 2;  //  6 MB
    f16* Q16   = (f16*)ws;   ws += nTok * E * 2;         // 16 MB
    f16* K16   = (f16*)ws;   ws += nTok * E * 2;         // 16 MB
    f16* Vt16  = (f16*)ws;   ws += nTok * E * 2;         // 16 MB ([b][e][s])
    f16* P16   = (f16*)ws;   ws += (long)Bb * S * S * 2; // 32 MB
    float* rsum = (float*)ws; ws += nTok * 4;            // 32 KB

    dim3 blk(256);

    hipMemsetAsync(rsum, 0, nTok * 4, stream);
    cvt_inp<<<(int)(nTok * E / 4 / 256), blk, 0, stream>>>(inp, inp16, (int)(nTok * E / 4));
    cvt_w3<<<3 * 1024, blk, 0, stream>>>(Wq, Wk, Wv, W3);

    // fused QKV: A = inp (8192x1024 tokens), Bt = W3 (3072x1024)
    gemm_bt<0, 128><<<dim3(3 * E / 128, (int)(nTok / 128), 1), blk, 0, stream>>>(
        inp16, 0, E, W3, 0, E, bq, bk, bv, nullptr,
        Q16, K16, Vt16, 0, E, nullptr);

    // P = exp(QK^T/32) + rowsum atomics (causal tile skip, heavy rows first)
    gemm_bt<2, 64><<<dim3(S / 64, S / 128, Bb), blk, 0, stream>>>(
        Q16, (long)S * E, E, K16, (long)S * E, E, nullptr, nullptr, nullptr, rsum,
        P16, nullptr, nullptr, (long)S * S, E, masked);

    // out = (P @ V)/rowsum  (Vt stored [b][e][s] -> Bt gemm), K causal-limited
    gemm_bt<3, 64><<<dim3(E / 64, S / 128, Bb), blk, 0, stream>>>(
        P16, (long)S * S, S, Vt16, (long)E * S, S, nullptr, nullptr, nullptr, rsum,
        out, nullptr, nullptr, (long)S * E, S, masked);
}